// Round 2
// baseline (3375.982 us; speedup 1.0000x reference)
//
#include <hip/hip_runtime.h>
#include <hip/hip_cooperative_groups.h>
#include <math.h>

namespace cg = cooperative_groups;

#define Tn 64
#define Bn 256
#define Hn 256
#define Vn 10000
#define NPAD 10112   // 79*128

typedef __attribute__((ext_vector_type(8))) short short8;
typedef __attribute__((ext_vector_type(4))) float f32x4;

__device__ inline unsigned short f2bf(float f) {
    unsigned int u = __float_as_uint(f);
    unsigned int r = (u + 0x7fff + ((u >> 16) & 1)) >> 16;
    return (unsigned short)r;
}

// ---------------------------------------------------------------------------
// whT[n][k] = wh[k][n]   (wh is [256][768], whT is [768][256]) fp32 for GRU
// ---------------------------------------------------------------------------
__global__ __launch_bounds__(256) void k_transpose_wh(const float* __restrict__ wh,
                                                      float* __restrict__ whT) {
    int n = blockIdx.x;
    int k = threadIdx.x;
    whT[n * 256 + k] = wh[k * 768 + n];
}

// ---------------------------------------------------------------------------
// dst[n][k] = bf16(src[k][ld*? + n]), k in 0..255 (4 k-tiles via blockIdx.y),
// zero-fill n >= nlimit.  dst is [Npad][256] bf16 row-major.
// ---------------------------------------------------------------------------
__global__ __launch_bounds__(256) void k_transpose_bf16(const float* __restrict__ src, int ld,
                                                        int nlimit, unsigned short* __restrict__ dst) {
    __shared__ float tl[64][65];
    const int n0 = blockIdx.x * 64, k0 = blockIdx.y * 64;
    const int tid = threadIdx.x;
    const int c = tid & 63, r0 = tid >> 6;
#pragma unroll
    for (int i = 0; i < 16; ++i) {
        int r = r0 + i * 4;
        tl[r][c] = (n0 + c < nlimit) ? src[(long)(k0 + r) * ld + n0 + c] : 0.f;
    }
    __syncthreads();
#pragma unroll
    for (int i = 0; i < 16; ++i) {
        int nr = r0 + i * 4;
        dst[(long)(n0 + nr) * 256 + k0 + c] = f2bf(tl[c][nr]);
    }
}

// ---------------------------------------------------------------------------
// float -> bf16 elementwise (poi_emb)
// ---------------------------------------------------------------------------
__global__ __launch_bounds__(256) void k_f2bf4(const float* __restrict__ src,
                                               unsigned short* __restrict__ dst, int n4) {
    int i = blockIdx.x * 256 + threadIdx.x;
    if (i < n4) {
        float4 v = ((const float4*)src)[i];
        ushort4 o;
        o.x = f2bf(v.x); o.y = f2bf(v.y); o.z = f2bf(v.z); o.w = f2bf(v.w);
        ((ushort4*)dst)[i] = o;
    }
}

// ---------------------------------------------------------------------------
// bf16 MFMA GEMM, C[M,N] = A[M,256] @ Bt[N,256]^T (+bias), m97 structure:
// 128x128 tile, BK=32, 4 waves (2x2), 4x4 frags of mfma_f32_16x16x32_bf16,
// global_load_lds 16B staging, linear LDS.
// GATHER=1: A row = Atab[gidx[m]], bias = biasN[n]           (GX: N=768)
// GATHER=0: A row = Atab[m],       bias = biasMN[(m&255)*N+n] (y: N=10000, guard)
// ---------------------------------------------------------------------------
template <int GATHER>
__global__ __launch_bounds__(256) void k_mfma(const unsigned short* __restrict__ Atab,
                                              const int* __restrict__ gidx,
                                              const unsigned short* __restrict__ Bt,
                                              const float* __restrict__ biasN,
                                              const float* __restrict__ biasMN,
                                              float* __restrict__ C,
                                              int N, int Nlimit) {
    __shared__ __align__(16) unsigned short Al[128 * 32];
    __shared__ __align__(16) unsigned short Bl[128 * 32];

    const int tid = threadIdx.x;
    const int wave = tid >> 6, lane = tid & 63;
    const int m0 = blockIdx.y * 128, n0 = blockIdx.x * 128;

    // staging: chunk c (16B = 8 bf16): row = c>>2, kchunk = c&3
    const int c0 = wave * 64 + lane;
    const int c1 = 256 + c0;
    long arow0, arow1;
    if (GATHER) { arow0 = gidx[m0 + (c0 >> 2)]; arow1 = gidx[m0 + (c1 >> 2)]; }
    else        { arow0 = m0 + (c0 >> 2);       arow1 = m0 + (c1 >> 2); }
    const unsigned short* Ap0 = Atab + arow0 * 256 + (c0 & 3) * 8;
    const unsigned short* Ap1 = Atab + arow1 * 256 + (c1 & 3) * 8;
    const unsigned short* Bp0 = Bt + (long)(n0 + (c0 >> 2)) * 256 + (c0 & 3) * 8;
    const unsigned short* Bp1 = Bt + (long)(n0 + (c1 >> 2)) * 256 + (c1 & 3) * 8;

    const int fr = lane & 15;   // frag row (A) / col (B)
    const int kq = lane >> 4;   // k-group
    const int wm = wave >> 1, wn = wave & 1;
    const int aoff = (wm * 64 + fr) * 32 + kq * 8;
    const int boff = (wn * 64 + fr) * 32 + kq * 8;

    f32x4 acc[4][4];
#pragma unroll
    for (int i = 0; i < 4; ++i)
#pragma unroll
        for (int j = 0; j < 4; ++j) acc[i][j] = (f32x4){0.f, 0.f, 0.f, 0.f};

    for (int k0 = 0; k0 < 256; k0 += 32) {
        __builtin_amdgcn_global_load_lds(
            (const __attribute__((address_space(1))) void*)(Ap0 + k0),
            (__attribute__((address_space(3))) void*)(Al + wave * 512), 16, 0, 0);
        __builtin_amdgcn_global_load_lds(
            (const __attribute__((address_space(1))) void*)(Ap1 + k0),
            (__attribute__((address_space(3))) void*)(Al + 2048 + wave * 512), 16, 0, 0);
        __builtin_amdgcn_global_load_lds(
            (const __attribute__((address_space(1))) void*)(Bp0 + k0),
            (__attribute__((address_space(3))) void*)(Bl + wave * 512), 16, 0, 0);
        __builtin_amdgcn_global_load_lds(
            (const __attribute__((address_space(1))) void*)(Bp1 + k0),
            (__attribute__((address_space(3))) void*)(Bl + 2048 + wave * 512), 16, 0, 0);
        __syncthreads();

        short8 af[4], bf[4];
#pragma unroll
        for (int i = 0; i < 4; ++i) af[i] = *(const short8*)(const void*)(Al + aoff + i * 512);
#pragma unroll
        for (int j = 0; j < 4; ++j) bf[j] = *(const short8*)(const void*)(Bl + boff + j * 512);
#pragma unroll
        for (int i = 0; i < 4; ++i)
#pragma unroll
            for (int j = 0; j < 4; ++j)
                acc[i][j] = __builtin_amdgcn_mfma_f32_16x16x32_bf16(af[i], bf[j], acc[i][j], 0, 0, 0);
        __syncthreads();
    }

#pragma unroll
    for (int i = 0; i < 4; ++i) {
#pragma unroll
        for (int j = 0; j < 4; ++j) {
            int n = n0 + wn * 64 + j * 16 + fr;
            if (!GATHER && n >= Nlimit) continue;
#pragma unroll
            for (int q = 0; q < 4; ++q) {
                int m = m0 + wm * 64 + i * 16 + kq * 4 + q;
                float v = acc[i][j][q];
                v += GATHER ? biasN[n] : biasMN[(long)(m & 255) * N + n];
                C[(long)m * N + n] = v;
            }
        }
    }
}

// ---------------------------------------------------------------------------
// fp32 tiled GEMM kept for UC only:
// UC[b, n] = user_emb[active_user[b]] @ fc_w[256:512] + fc_b
// ---------------------------------------------------------------------------
__global__ __launch_bounds__(256) void k_gemm_uc(const float* __restrict__ Abase,
                                                 const int* __restrict__ gidx,
                                                 const float* __restrict__ Bg,
                                                 const float* __restrict__ bias,
                                                 float* __restrict__ C,
                                                 int N, int ldb, int koff) {
    __shared__ float As[64][64];
    __shared__ float Bs[64][64];
    const int tid = threadIdx.x;
    const int m0 = blockIdx.y * 64;
    const int n0 = blockIdx.x * 64;
    const int m_l = tid & 63;
    const int kq = tid >> 6;
    long arow = (long)gidx[m0 + m_l];
    const float* Ap = Abase + arow * 256;
    const int nc = tid & 15;
    const int kr0 = tid >> 4;
    const int ty = tid >> 4, tx = tid & 15;

    float acc[4][4];
#pragma unroll
    for (int r = 0; r < 4; ++r)
#pragma unroll
        for (int c = 0; c < 4; ++c) acc[r][c] = 0.f;

    for (int k0 = 0; k0 < 256; k0 += 64) {
#pragma unroll
        for (int i = 0; i < 4; ++i) {
            int kc = kq + i * 4;
            float4 a4 = *(const float4*)(Ap + k0 + kc * 4);
            As[kc * 4 + 0][m_l] = a4.x;
            As[kc * 4 + 1][m_l] = a4.y;
            As[kc * 4 + 2][m_l] = a4.z;
            As[kc * 4 + 3][m_l] = a4.w;
        }
#pragma unroll
        for (int i = 0; i < 4; ++i) {
            int kr = kr0 + i * 16;
            int col = n0 + nc * 4;
            float4 b4;
            if (col < N) b4 = *(const float4*)(Bg + (long)(koff + k0 + kr) * ldb + col);
            else b4 = make_float4(0.f, 0.f, 0.f, 0.f);
            *(float4*)&Bs[kr][nc * 4] = b4;
        }
        __syncthreads();
#pragma unroll
        for (int kk = 0; kk < 64; ++kk) {
            float4 a4 = *(const float4*)&As[kk][ty * 4];
            float4 b4 = *(const float4*)&Bs[kk][tx * 4];
            acc[0][0] += a4.x * b4.x; acc[0][1] += a4.x * b4.y;
            acc[0][2] += a4.x * b4.z; acc[0][3] += a4.x * b4.w;
            acc[1][0] += a4.y * b4.x; acc[1][1] += a4.y * b4.y;
            acc[1][2] += a4.y * b4.z; acc[1][3] += a4.y * b4.w;
            acc[2][0] += a4.z * b4.x; acc[2][1] += a4.z * b4.y;
            acc[2][2] += a4.z * b4.z; acc[2][3] += a4.z * b4.w;
            acc[3][0] += a4.w * b4.x; acc[3][1] += a4.w * b4.y;
            acc[3][2] += a4.w * b4.z; acc[3][3] += a4.w * b4.w;
        }
        __syncthreads();
    }
#pragma unroll
    for (int r = 0; r < 4; ++r) {
        int m = m0 + ty * 4 + r;
#pragma unroll
        for (int c = 0; c < 4; ++c) {
            int n = n0 + tx * 4 + c;
            if (n < N) C[(long)m * N + n] = acc[r][c] + bias[n];
        }
    }
}

// ---------------------------------------------------------------------------
// Persistent cooperative GRU: 256 blocks = (16 h-groups) x (16 b-groups).
// wh slice staged in LDS ONCE; h round-trips through global; grid.sync per step.
// ---------------------------------------------------------------------------
__global__ __launch_bounds__(256, 1) void k_gru_all(const float* __restrict__ GX,   // [T,B,768]
                                                    const float* __restrict__ h0,   // [B,256]
                                                    const float* __restrict__ whT,  // [768,256]
                                                    float* __restrict__ OUT) {      // [T,B,256]
    cg::grid_group grid = cg::this_grid();
    __shared__ float ws[48][260];
    __shared__ float hs[16][260];

    const int tid = threadIdx.x;
    const int hg = blockIdx.x & 15, bg = blockIdx.x >> 4;
    const int h0c = hg * 16, b0 = bg * 16;

#pragma unroll
    for (int i = 0; i < 12; ++i) {
        int idx = tid + i * 256;
        int row = idx >> 6, c4 = idx & 63;
        int g = row >> 4, hh = row & 15;
        *(float4*)&ws[row][c4 * 4] = *(const float4*)(whT + (g * 256 + h0c + hh) * 256 + c4 * 4);
    }

    const int tb = tid >> 4, th = tid & 15;
    const int b = b0 + tb, h = h0c + th;

    for (int t = 0; t < Tn; ++t) {
        const float* hp = t ? (OUT + (long)(t - 1) * (Bn * Hn)) : h0;
#pragma unroll
        for (int i = 0; i < 4; ++i) {
            int idx = tid + i * 256;
            int row = idx >> 6, c4 = idx & 63;
            *(float4*)&hs[row][c4 * 4] = *(const float4*)(hp + (b0 + row) * 256 + c4 * 4);
        }
        __syncthreads();

        float ra = 0.f, za = 0.f, na = 0.f;
#pragma unroll 16
        for (int k4 = 0; k4 < 64; ++k4) {
            float4 h4 = *(const float4*)&hs[tb][k4 * 4];
            float4 wr = *(const float4*)&ws[th][k4 * 4];
            float4 wz = *(const float4*)&ws[16 + th][k4 * 4];
            float4 wn = *(const float4*)&ws[32 + th][k4 * 4];
            ra += h4.x * wr.x + h4.y * wr.y + h4.z * wr.z + h4.w * wr.w;
            za += h4.x * wz.x + h4.y * wz.y + h4.z * wz.z + h4.w * wz.w;
            na += h4.x * wn.x + h4.y * wn.y + h4.z * wn.z + h4.w * wn.w;
        }
        long gxb = ((long)t * Bn + b) * 768;
        float gxr = GX[gxb + h];
        float gxz = GX[gxb + 256 + h];
        float gxn = GX[gxb + 512 + h];
        float hpv = hs[tb][h];
        float r = 1.f / (1.f + expf(-(gxr + ra)));
        float z = 1.f / (1.f + expf(-(gxz + za)));
        float nn = tanhf(gxn + r * na);
        OUT[(long)t * (Bn * Hn) + b * 256 + h] = (1.f - z) * nn + z * hpv;
        grid.sync();
    }
}

// ---------------------------------------------------------------------------
// Spatio-temporal weights + causal weighted average; writes OUTW in bf16.
// ---------------------------------------------------------------------------
__global__ __launch_bounds__(256) void k_stw(const float* __restrict__ t_in,
                                             const float* __restrict__ s_in,
                                             const float* __restrict__ OUT,
                                             unsigned short* __restrict__ OUTW) {
    __shared__ float tl[64];
    __shared__ float sl[64][2];
    __shared__ float w[64][64];
    __shared__ float swinv[64];
    __shared__ float outc[16][256];

    const int b = blockIdx.x;
    const int tid = threadIdx.x;

    if (tid < 64) tl[tid] = t_in[tid * Bn + b];
    if (tid < 128) {
        int i = tid >> 1, c = tid & 1;
        sl[i][c] = s_in[(i * Bn + b) * 2 + c];
    }
    __syncthreads();

    const float TWO_PI_OVER_DAY = 6.283185307179586f / 86400.0f;
    const float LT_OVER_DAY = 0.1f / 86400.0f;
#pragma unroll
    for (int e = tid; e < 4096; e += 256) {
        int i = e >> 6, j = e & 63;
        float v = 0.f;
        if (j <= i) {
            float dt = tl[i] - tl[j];
            float dx = sl[i][0] - sl[j][0];
            float dy = sl[i][1] - sl[j][1];
            float dsd = sqrtf(dx * dx + dy * dy);
            float ft = 0.5f * (cosf(dt * TWO_PI_OVER_DAY) + 1.f) * expf(-dt * LT_OVER_DAY);
            float fs = expf(-dsd * 100.0f);
            v = ft * fs + 1e-10f;
        }
        w[i][j] = v;
    }
    __syncthreads();
    if (tid < 64) {
        float s = 0.f;
        for (int j = 0; j <= tid; ++j) s += w[tid][j];
        swinv[tid] = 1.f / s;
    }
    __syncthreads();

    for (int it = 0; it < 4; ++it) {
        float accs[16];
#pragma unroll
        for (int q = 0; q < 16; ++q) accs[q] = 0.f;
        for (int jt = 0; jt <= it; ++jt) {
            __syncthreads();
#pragma unroll
            for (int i2 = 0; i2 < 4; ++i2) {
                int idx = tid + i2 * 256;
                int jr = idx >> 6, c4 = idx & 63;
                *(float4*)&outc[jr][c4 * 4] =
                    *(const float4*)(OUT + ((long)(jt * 16 + jr) * Bn + b) * Hn + c4 * 4);
            }
            __syncthreads();
#pragma unroll
            for (int i_l = 0; i_l < 16; ++i_l) {
                int i = it * 16 + i_l;
                int jmax = (jt < it) ? 15 : i_l;
                float a = accs[i_l];
                for (int j_l = 0; j_l <= jmax; ++j_l)
                    a += w[i][jt * 16 + j_l] * outc[j_l][tid];
                accs[i_l] = a;
            }
        }
#pragma unroll
        for (int i_l = 0; i_l < 16; ++i_l) {
            int i = it * 16 + i_l;
            OUTW[((long)i * Bn + b) * Hn + tid] = f2bf(accs[i_l] * swinv[i]);
        }
    }
}

// ---------------------------------------------------------------------------
__global__ __launch_bounds__(256) void k_copy4(const float* __restrict__ src,
                                               float* __restrict__ dst, int n4) {
    int i = blockIdx.x * 256 + threadIdx.x;
    if (i < n4) ((float4*)dst)[i] = ((const float4*)src)[i];
}

// ---------------------------------------------------------------------------
extern "C" void kernel_launch(void* const* d_in, const int* in_sizes, int n_in,
                              void* d_out, int out_size, void* d_ws, size_t ws_size,
                              hipStream_t stream) {
    const int*   x     = (const int*)  d_in[0];
    const float* t_in  = (const float*)d_in[1];
    const float* s_in  = (const float*)d_in[2];
    const float* h0    = (const float*)d_in[3];
    const int*   auser = (const int*)  d_in[4];
    const float* poi   = (const float*)d_in[5];
    const float* uemb  = (const float*)d_in[6];
    const float* wx    = (const float*)d_in[7];
    const float* wh    = (const float*)d_in[8];
    const float* gb    = (const float*)d_in[9];
    const float* fcw   = (const float*)d_in[10];
    const float* fcb   = (const float*)d_in[11];

    char* w = (char*)d_ws;
    float*          GX   = (float*)w;                                  // 50,331,648 B [T,B,768]
    unsigned short* OUTW = (unsigned short*)w;                         // aliases GX (GX dead before stw)
    float*          OUT  = (float*)(w + 50331648);                     // 16,777,216 B [T,B,256]
    float*          UC   = (float*)(w + 67108864);                     // 10,240,000 B [B,V]
    float*          WHT  = (float*)(w + 77348864);                     //    786,432 B [768,256]
    unsigned short* POIB = (unsigned short*)(w + 78135296);            //  5,120,000 B [V,256] bf16
    unsigned short* WXT  = (unsigned short*)(w + 83255296);            //    393,216 B [768,256] bf16
    unsigned short* FCWT = (unsigned short*)(w + 83648512);            //  5,177,344 B [NPAD,256] bf16

    float* y    = (float*)d_out;
    float* hfin = y + (long)Tn * Bn * Vn;

    // --- prep ---
    k_transpose_wh<<<768, 256, 0, stream>>>(wh, WHT);
    k_f2bf4<<<2500, 256, 0, stream>>>(poi, POIB, (Vn * Hn) / 4);
    k_transpose_bf16<<<dim3(12, 4), 256, 0, stream>>>(wx, 768, 768, WXT);
    k_transpose_bf16<<<dim3(NPAD / 64, 4), 256, 0, stream>>>(fcw, Vn, Vn, FCWT);

    // GX = bf16(poi_emb[x]) @ bf16(wx) + gru_b   (M=16384, N=768, K=256)
    k_mfma<1><<<dim3(6, 128), 256, 0, stream>>>(POIB, x, WXT, gb, nullptr, GX, 768, 768);

    // UC = user_emb[active_user] @ fc_w[256:512] + fc_b  (fp32)
    k_gemm_uc<<<dim3(157, 4), 256, 0, stream>>>(uemb, auser, fcw, fcb, UC, Vn, Vn, 256);

    // GRU recurrence: one cooperative kernel, 64 steps
    {
        const float* gxp = GX; const float* h0p = h0; const float* whtp = WHT; float* outp = OUT;
        void* gargs[] = {(void*)&gxp, (void*)&h0p, (void*)&whtp, (void*)&outp};
        hipLaunchCooperativeKernel(reinterpret_cast<void*>(&k_gru_all),
                                   dim3(256), dim3(256), gargs, 0, stream);
    }
    k_copy4<<<64, 256, 0, stream>>>(OUT + (long)(Tn - 1) * Bn * Hn, hfin, (Bn * Hn) / 4);

    // causal spatio-temporal weighted average -> OUTW (bf16)
    k_stw<<<256, 256, 0, stream>>>(t_in, s_in, OUT, OUTW);

    // y = OUTW @ fc_w[0:256] + UC[b]   (M=16384, N=10000, K=256) via MFMA
    k_mfma<0><<<dim3(NPAD / 128, 128), 256, 0, stream>>>(OUTW, nullptr, FCWT, nullptr, UC, y, Vn, Vn);
}